// Round 16
// baseline (136.615 us; speedup 1.0000x reference)
//
#include <hip/hip_runtime.h>

typedef __attribute__((ext_vector_type(8))) short short8;
typedef __attribute__((ext_vector_type(4))) float f32x4;
typedef unsigned short u16;
typedef unsigned int u32;

#define NNODES 65536
#define FDIM 128

__device__ __forceinline__ u16 f2bf(float f) {
    u32 u = __float_as_uint(f);
    u32 r = (u + 0x7fffu + ((u >> 16) & 1u)) >> 16;   // RNE
    return (u16)r;
}
__device__ __forceinline__ u32 pack2bf(float lo, float hi) {
    return ((u32)f2bf(hi) << 16) | f2bf(lo);
}
__device__ __forceinline__ float bflo(u32 g) { return __uint_as_float(g << 16); }
__device__ __forceinline__ float bfhi(u32 g) { return __uint_as_float(g & 0xffff0000u); }

// ---------- prep: rowptr + wT casts only ----------
__global__ void prep_kernel(const int* __restrict__ erow, int* __restrict__ rowptr,
                            const float* __restrict__ w1, u16* __restrict__ wt1,
                            const float* __restrict__ w2, u16* __restrict__ wt2,
                            const float* __restrict__ w3, u16* __restrict__ wt3,
                            int n, int e) {
    const int b = blockIdx.x;
    const int tid = threadIdx.x;
    if (b < 257) {                               // rowptr
        int r = b * 256 + tid;
        if (r > n) return;
        int lo = 0, hi = e;
        while (lo < hi) {
            int mid = (lo + hi) >> 1;
            if (erow[mid] < r) lo = mid + 1; else hi = mid;
        }
        rowptr[r] = lo;
    } else {                                     // weight transpose-cast
        const float* w; u16* wt; int idx;
        if (b < 321)      { w = w1; wt = wt1; idx = (b - 257) * 256 + tid; }
        else if (b < 385) { w = w2; wt = wt2; idx = (b - 321) * 256 + tid; }
        else              { w = w3; wt = wt3; idx = (b - 385) * 256 + tid; }
        const int K = 128;
        const int NC = (b < 385) ? 128 : 64;
        if (idx >= K * NC) return;
        int nn = idx / K, k = idx - nn * K;
        wt[idx] = f2bf(w[k * NC + nn]);
    }
}

// ---------- SpMM v9: feature-sliced for per-XCD L2 residency ----------
// 4 slices x 32 features (64B). slice q = blockIdx & 3: under round-robin
// block->XCD dispatch, XCD k always serves slice k&3 -> its 4MB table slice is
// L2-RESIDENT -> gathers hit L2 (~200cy) instead of L3/HBM (~600+cy). Wave =
// R7 shape: 2 rows, slot=lane>>4 (edge slot), fg=lane&15 (4B of the slice ->
// 64B coalesced gather, 1 VGPR payload). Rounds 1+2 (deg<=16, 96% of rows)
// issue all 8 gathers upfront (8 VGPR payload -- no R13 spill bomb). 2-stage
// butterfly on 2 accs/row; slot 0/1 store rows A/B (64B per row-slice).
template<bool RELU>
__global__ __launch_bounds__(256, 6)
void spmm_kernel(const u16* __restrict__ h, const int* __restrict__ rowptr,
                 const int* __restrict__ col, const float* __restrict__ val,
                 u16* __restrict__ y, int n) {
    const int lane = threadIdx.x & 63;
    const int wave = threadIdx.x >> 6;
    const int q    = blockIdx.x & 3;             // feature slice (XCD-pinned)
    const int rA   = (blockIdx.x >> 2) * 8 + wave * 2;
    if (rA >= n) return;
    const int slot = lane >> 4;
    const int fg   = lane & 15;
    const u16* hf  = h + q * 32 + fg * 2;

    const int sA = rowptr[rA], eA = rowptr[rA + 1], eB = rowptr[rA + 2];

    // --- meta rounds 1+2 (edges s+slot+4k, k=0..3), both rows ---
    const int iA = sA + slot, iB = eA + slot;
    int cA[4], cB[4]; float vA[4], vB[4];
#pragma unroll
    for (int k = 0; k < 4; ++k) {
        int ia = iA + 4 * k;
        bool oa = ia < eA;
        cA[k] = oa ? col[ia] : 0;
        vA[k] = oa ? val[ia] : 0.f;
        int ib = iB + 4 * k;
        bool ob = ib < eB;
        cB[k] = ob ? col[ib] : 0;
        vB[k] = ob ? val[ib] : 0.f;
    }

    // --- 8 gathers back-to-back (1 VGPR each) ---
    u32 gA[4], gB[4];
#pragma unroll
    for (int k = 0; k < 4; ++k)
        gA[k] = *reinterpret_cast<const u32*>(hf + (size_t)cA[k] * FDIM);
#pragma unroll
    for (int k = 0; k < 4; ++k)
        gB[k] = *reinterpret_cast<const u32*>(hf + (size_t)cB[k] * FDIM);

    float a0 = 0.f, a1 = 0.f, b0 = 0.f, b1 = 0.f;
#pragma unroll
    for (int k = 0; k < 4; ++k) {
        a0 = fmaf(vA[k], bflo(gA[k]), a0);
        a1 = fmaf(vA[k], bfhi(gA[k]), a1);
        b0 = fmaf(vB[k], bflo(gB[k]), b0);
        b1 = fmaf(vB[k], bfhi(gB[k]), b1);
    }

    // --- remainder (deg > 16, rare): 2 gathers in flight per row ---
    int jA = iA + 16;
    while (jA < eA) {
        int  c0 = col[jA];            float v0 = val[jA];
        bool ok = jA + 4 < eA;
        int  c1 = ok ? col[jA + 4] : 0; float v1 = ok ? val[jA + 4] : 0.f;
        u32 g0 = *reinterpret_cast<const u32*>(hf + (size_t)c0 * FDIM);
        u32 g1 = *reinterpret_cast<const u32*>(hf + (size_t)c1 * FDIM);
        a0 = fmaf(v0, bflo(g0), a0); a1 = fmaf(v0, bfhi(g0), a1);
        a0 = fmaf(v1, bflo(g1), a0); a1 = fmaf(v1, bfhi(g1), a1);
        jA += 8;
    }
    int jB = iB + 16;
    while (jB < eB) {
        int  c0 = col[jB];            float v0 = val[jB];
        bool ok = jB + 4 < eB;
        int  c1 = ok ? col[jB + 4] : 0; float v1 = ok ? val[jB + 4] : 0.f;
        u32 g0 = *reinterpret_cast<const u32*>(hf + (size_t)c0 * FDIM);
        u32 g1 = *reinterpret_cast<const u32*>(hf + (size_t)c1 * FDIM);
        b0 = fmaf(v0, bflo(g0), b0); b1 = fmaf(v0, bfhi(g0), b1);
        b0 = fmaf(v1, bflo(g1), b0); b1 = fmaf(v1, bfhi(g1), b1);
        jB += 8;
    }

    // --- butterfly across the 4 slots ---
#pragma unroll
    for (int m = 16; m <= 32; m <<= 1) {
        a0 += __shfl_xor(a0, m, 64); a1 += __shfl_xor(a1, m, 64);
        b0 += __shfl_xor(b0, m, 64); b1 += __shfl_xor(b1, m, 64);
    }

    if (RELU) {
        a0 = fmaxf(a0, 0.f); a1 = fmaxf(a1, 0.f);
        b0 = fmaxf(b0, 0.f); b1 = fmaxf(b1, 0.f);
    }
    if (slot == 0)
        *reinterpret_cast<u32*>(y + (size_t)rA * FDIM + q * 32 + fg * 2) = pack2bf(a0, a1);
    if (slot == 1)
        *reinterpret_cast<u32*>(y + (size_t)(rA + 1) * FDIM + q * 32 + fg * 2) = pack2bf(b0, b1);
}

// ---------- GEMM: LDS-staged weights, one 16-row chunk per wave ----------
template<int NT, bool RELU, bool OUT_BF16, bool FP32A>
__global__ __launch_bounds__(256, 4)
void gemm_kernel(const void* __restrict__ Av, const u16* __restrict__ WT,
                 void* __restrict__ out, int M) {
    constexpr int NC = NT * 16;
    constexpr int LSTR = 136;                 // u16: 128 data + 8 pad
    __shared__ u16 wlds[NC * LSTR];

    const int t = threadIdx.x;
    const int fr = t & 15;
#pragma unroll
    for (int n = t >> 4; n < NC; n += 16)
        *reinterpret_cast<uint4*>(&wlds[n * LSTR + fr * 8]) =
            *reinterpret_cast<const uint4*>(&WT[(size_t)n * 128 + fr * 8]);
    __syncthreads();

    const int lane = t & 63;
    const int dn = lane & 15;
    const int kg = lane >> 4;
    const int r0 = (blockIdx.x * 4 + (t >> 6)) << 4;
    if (r0 >= M) return;

    f32x4 acc[NT];
#pragma unroll
    for (int nt = 0; nt < NT; ++nt) acc[nt] = (f32x4){0.f, 0.f, 0.f, 0.f};

#pragma unroll
    for (int s = 0; s < 4; ++s) {
        short8 a;
        if (FP32A) {
            const float* Af = (const float*)Av + (size_t)(r0 + dn) * 128 + s * 32 + kg * 8;
            float4 x0 = *reinterpret_cast<const float4*>(Af);
            float4 x1 = *reinterpret_cast<const float4*>(Af + 4);
            a[0] = (short)f2bf(x0.x); a[1] = (short)f2bf(x0.y);
            a[2] = (short)f2bf(x0.z); a[3] = (short)f2bf(x0.w);
            a[4] = (short)f2bf(x1.x); a[5] = (short)f2bf(x1.y);
            a[6] = (short)f2bf(x1.z); a[7] = (short)f2bf(x1.w);
        } else {
            a = *reinterpret_cast<const short8*>(
                (const u16*)Av + (size_t)(r0 + dn) * 128 + s * 32 + kg * 8);
        }
#pragma unroll
        for (int nt = 0; nt < NT; ++nt) {
            short8 b = *reinterpret_cast<const short8*>(
                &wlds[(nt * 16 + dn) * LSTR + s * 32 + kg * 8]);
            acc[nt] = __builtin_amdgcn_mfma_f32_16x16x32_bf16(b, a, acc[nt], 0, 0, 0);
        }
    }

    const int row = r0 + dn;
#pragma unroll
    for (int nt = 0; nt < NT; ++nt) {
        float v0 = acc[nt][0], v1 = acc[nt][1], v2 = acc[nt][2], v3 = acc[nt][3];
        if (RELU) {
            v0 = fmaxf(v0, 0.f); v1 = fmaxf(v1, 0.f);
            v2 = fmaxf(v2, 0.f); v3 = fmaxf(v3, 0.f);
        }
        if (OUT_BF16) {
            uint2 p; p.x = pack2bf(v0, v1); p.y = pack2bf(v2, v3);
            *reinterpret_cast<uint2*>(
                (u16*)out + (size_t)row * NC + nt * 16 + kg * 4) = p;
        } else {
            float4 p = make_float4(v0, v1, v2, v3);
            *reinterpret_cast<float4*>(
                (float*)out + (size_t)row * NC + nt * 16 + kg * 4) = p;
        }
    }
}

// ---------- Fused GEMM2+GEMM3: out = relu(Y @ W2) @ W3, no h2 round-trip ----------
__global__ __launch_bounds__(256, 2)
void gemm23_kernel(const u16* __restrict__ A, const u16* __restrict__ WT2,
                   const u16* __restrict__ WT3, float* __restrict__ out, int M) {
    constexpr int LSTR = 136;
    __shared__ u16 w2l[128 * LSTR];           // 34816 B
    __shared__ u16 h2l[4][16 * LSTR];         // 17408 B (4.3KB per wave, private)

    const int t = threadIdx.x;
    const int fr = t & 15;
#pragma unroll
    for (int n = t >> 4; n < 128; n += 16)
        *reinterpret_cast<uint4*>(&w2l[n * LSTR + fr * 8]) =
            *reinterpret_cast<const uint4*>(&WT2[(size_t)n * 128 + fr * 8]);

    const int wave = t >> 6;
    const int lane = t & 63;
    const int dn = lane & 15;
    const int kg = lane >> 4;

    short8 bw3[4][4];
#pragma unroll
    for (int nt = 0; nt < 4; ++nt)
#pragma unroll
        for (int s = 0; s < 4; ++s)
            bw3[nt][s] = *reinterpret_cast<const short8*>(
                &WT3[(size_t)(nt * 16 + dn) * 128 + s * 32 + kg * 8]);

    __syncthreads();

    const int r0 = (blockIdx.x * 4 + wave) << 4;
    if (r0 >= M) return;

    f32x4 acc2[8];
#pragma unroll
    for (int nt = 0; nt < 8; ++nt) acc2[nt] = (f32x4){0.f, 0.f, 0.f, 0.f};
#pragma unroll
    for (int s = 0; s < 4; ++s) {
        short8 a = *reinterpret_cast<const short8*>(
            &A[(size_t)(r0 + dn) * 128 + s * 32 + kg * 8]);
#pragma unroll
        for (int nt = 0; nt < 8; ++nt) {
            short8 b = *reinterpret_cast<const short8*>(
                &w2l[(nt * 16 + dn) * LSTR + s * 32 + kg * 8]);
            acc2[nt] = __builtin_amdgcn_mfma_f32_16x16x32_bf16(b, a, acc2[nt], 0, 0, 0);
        }
    }

    u16* my = h2l[wave];
#pragma unroll
    for (int nt = 0; nt < 8; ++nt) {
        float v0 = fmaxf(acc2[nt][0], 0.f), v1 = fmaxf(acc2[nt][1], 0.f);
        float v2 = fmaxf(acc2[nt][2], 0.f), v3 = fmaxf(acc2[nt][3], 0.f);
        uint2 p; p.x = pack2bf(v0, v1); p.y = pack2bf(v2, v3);
        *reinterpret_cast<uint2*>(&my[dn * LSTR + nt * 16 + kg * 4]) = p;
    }

    f32x4 acc3[4];
#pragma unroll
    for (int nt = 0; nt < 4; ++nt) acc3[nt] = (f32x4){0.f, 0.f, 0.f, 0.f};
#pragma unroll
    for (int s = 0; s < 4; ++s) {
        short8 a = *reinterpret_cast<const short8*>(
            &my[dn * LSTR + s * 32 + kg * 8]);
#pragma unroll
        for (int nt = 0; nt < 4; ++nt)
            acc3[nt] = __builtin_amdgcn_mfma_f32_16x16x32_bf16(bw3[nt][s], a, acc3[nt], 0, 0, 0);
    }

    const int row = r0 + dn;
#pragma unroll
    for (int nt = 0; nt < 4; ++nt)
        *reinterpret_cast<float4*>(out + (size_t)row * 64 + nt * 16 + kg * 4) =
            make_float4(acc3[nt][0], acc3[nt][1], acc3[nt][2], acc3[nt][3]);
}

extern "C" void kernel_launch(void* const* d_in, const int* in_sizes, int n_in,
                              void* d_out, int out_size, void* d_ws, size_t ws_size,
                              hipStream_t stream) {
    const float* x    = (const float*)d_in[0];
    const float* w1   = (const float*)d_in[1];
    const float* w2   = (const float*)d_in[2];
    const float* w3   = (const float*)d_in[3];
    const int*   erow = (const int*)d_in[4];
    const int*   ecol = (const int*)d_in[5];
    const float* eval = (const float*)d_in[6];
    float* out = (float*)d_out;

    const int N = in_sizes[0] / FDIM;
    const int E = in_sizes[4];

    char* ws = (char*)d_ws;
    int* rowptr = (int*)ws;                                  // (N+1)*4
    u16* wt1 = (u16*)(ws + (512 << 10));                     // 32KB
    u16* wt2 = wt1 + 128 * 128;                              // 32KB
    u16* wt3 = wt2 + 128 * 128;                              // 16KB
    u16* zbuf = (u16*)(ws + (1 << 20));                      // 16MB bf16 [N][128]
    u16* hbuf = (u16*)(ws + (18u << 20));                    // 16MB bf16 [N][128]

    prep_kernel<<<417, 256, 0, stream>>>(erow, rowptr, w1, wt1, w2, wt2, w3, wt3, N, E);
    // z = x @ W1 (fp32 A direct; linearity: spmm(x)@W1 == spmm(x@W1))
    gemm_kernel<8, false, true, true><<<N / 64, 256, 0, stream>>>(x, wt1, zbuf, N);
    // h1 = relu(spmm(z))  -- 4 feature-slices x N/8 row-chunks
    spmm_kernel<true><<<N / 2, 256, 0, stream>>>(zbuf, rowptr, ecol, eval, hbuf, N);
    // y = spmm(h1)
    spmm_kernel<false><<<N / 2, 256, 0, stream>>>(hbuf, rowptr, ecol, eval, zbuf, N);
    // out = relu(y @ W2) @ W3
    gemm23_kernel<<<N / 64, 256, 0, stream>>>(zbuf, wt2, wt3, out, N);
}

// Round 17
// 89.640 us; speedup vs baseline: 1.5240x; 1.5240x over previous
//
#include <hip/hip_runtime.h>

typedef __attribute__((ext_vector_type(8))) short short8;
typedef __attribute__((ext_vector_type(4))) float f32x4;
typedef unsigned short u16;
typedef unsigned int u32;

#define NNODES 65536
#define FDIM 128

__device__ __forceinline__ u16 f2bf(float f) {
    u32 u = __float_as_uint(f);
    u32 r = (u + 0x7fffu + ((u >> 16) & 1u)) >> 16;   // RNE
    return (u16)r;
}
__device__ __forceinline__ u32 pack2bf(float lo, float hi) {
    return ((u32)f2bf(hi) << 16) | f2bf(lo);
}

// ---------- prep: rowptr + wT casts only ----------
__global__ void prep_kernel(const int* __restrict__ erow, int* __restrict__ rowptr,
                            const float* __restrict__ w1, u16* __restrict__ wt1,
                            const float* __restrict__ w2, u16* __restrict__ wt2,
                            const float* __restrict__ w3, u16* __restrict__ wt3,
                            int n, int e) {
    const int b = blockIdx.x;
    const int tid = threadIdx.x;
    if (b < 257) {                               // rowptr
        int r = b * 256 + tid;
        if (r > n) return;
        int lo = 0, hi = e;
        while (lo < hi) {
            int mid = (lo + hi) >> 1;
            if (erow[mid] < r) lo = mid + 1; else hi = mid;
        }
        rowptr[r] = lo;
    } else {                                     // weight transpose-cast
        const float* w; u16* wt; int idx;
        if (b < 321)      { w = w1; wt = wt1; idx = (b - 257) * 256 + tid; }
        else if (b < 385) { w = w2; wt = wt2; idx = (b - 321) * 256 + tid; }
        else              { w = w3; wt = wt3; idx = (b - 385) * 256 + tid; }
        const int K = 128;
        const int NC = (b < 385) ? 128 : 64;
        if (idx >= K * NC) return;
        int nn = idx / K, k = idx - nn * K;
        wt[idx] = f2bf(w[k * NC + nn]);
    }
}

// ---------- SpMM v8+nt: 1 row/wave, scalar meta, 1-VGPR gathers, NT y-stores ----------
// R14's measured-best structure. New: y stores are NON-TEMPORAL (bypass L2) so
// the 16MB write stream stops evicting gather-table lines from each XCD's 4MB
// L2 (theory: write-allocate eviction is part of the 39MB random re-fetch).
template<bool RELU>
__global__ __launch_bounds__(256, 8)
void spmm_kernel(const u16* __restrict__ h, const int* __restrict__ rowptr,
                 const int* __restrict__ col, const float* __restrict__ val,
                 u16* __restrict__ y, int n) {
    const int lane = threadIdx.x & 63;
    int r = __builtin_amdgcn_readfirstlane((int)((blockIdx.x * blockDim.x + threadIdx.x) >> 6));
    if (r >= n) return;
    const int s = rowptr[r], e = rowptr[r + 1];   // uniform -> s_load
    const int deg = e - s;
    const u16* hl = h + lane * 2;

    float a0 = 0.f, a1 = 0.f;

    if (deg <= 8) {
        int   cc[8]; float vv[8];
#pragma unroll
        for (int j = 0; j < 8; ++j) {
            bool ok = j < deg;
            cc[j] = ok ? col[s + j] : 0;
            vv[j] = ok ? val[s + j] : 0.f;
        }
        u32 g[8];
#pragma unroll
        for (int j = 0; j < 8; ++j)
            g[j] = *reinterpret_cast<const u32*>(hl + (size_t)cc[j] * FDIM);
#pragma unroll
        for (int j = 0; j < 8; ++j) {
            a0 = fmaf(vv[j], __uint_as_float(g[j] << 16), a0);
            a1 = fmaf(vv[j], __uint_as_float(g[j] & 0xffff0000u), a1);
        }
    } else {
        int   cc[16]; float vv[16];
#pragma unroll
        for (int j = 0; j < 16; ++j) {
            bool ok = j < deg;
            cc[j] = ok ? col[s + j] : 0;
            vv[j] = ok ? val[s + j] : 0.f;
        }
        u32 g[16];
#pragma unroll
        for (int j = 0; j < 16; ++j)
            g[j] = *reinterpret_cast<const u32*>(hl + (size_t)cc[j] * FDIM);
#pragma unroll
        for (int j = 0; j < 16; ++j) {
            a0 = fmaf(vv[j], __uint_as_float(g[j] << 16), a0);
            a1 = fmaf(vv[j], __uint_as_float(g[j] & 0xffff0000u), a1);
        }
        // serial 2-wide tail (deg > 16, rare)
        int j = s + 16;
        while (j < e) {
            int  c0 = col[j];     float v0 = val[j];
            bool ok1 = j + 1 < e;
            int  c1 = ok1 ? col[j + 1] : 0;
            float v1 = ok1 ? val[j + 1] : 0.f;
            u32 g0 = *reinterpret_cast<const u32*>(hl + (size_t)c0 * FDIM);
            u32 g1 = *reinterpret_cast<const u32*>(hl + (size_t)c1 * FDIM);
            a0 = fmaf(v0, __uint_as_float(g0 << 16), a0);
            a1 = fmaf(v0, __uint_as_float(g0 & 0xffff0000u), a1);
            a0 = fmaf(v1, __uint_as_float(g1 << 16), a0);
            a1 = fmaf(v1, __uint_as_float(g1 & 0xffff0000u), a1);
            j += 2;
        }
    }

    if (RELU) { a0 = fmaxf(a0, 0.f); a1 = fmaxf(a1, 0.f); }
    __builtin_nontemporal_store(pack2bf(a0, a1),
        reinterpret_cast<u32*>(y + (size_t)r * FDIM + lane * 2));
}

// ---------- GEMM: LDS-staged weights, one 16-row chunk per wave ----------
template<int NT, bool RELU, bool OUT_BF16, bool FP32A>
__global__ __launch_bounds__(256, 4)
void gemm_kernel(const void* __restrict__ Av, const u16* __restrict__ WT,
                 void* __restrict__ out, int M) {
    constexpr int NC = NT * 16;
    constexpr int LSTR = 136;                 // u16: 128 data + 8 pad
    __shared__ u16 wlds[NC * LSTR];

    const int t = threadIdx.x;
    const int fr = t & 15;
#pragma unroll
    for (int n = t >> 4; n < NC; n += 16)
        *reinterpret_cast<uint4*>(&wlds[n * LSTR + fr * 8]) =
            *reinterpret_cast<const uint4*>(&WT[(size_t)n * 128 + fr * 8]);
    __syncthreads();

    const int lane = t & 63;
    const int dn = lane & 15;
    const int kg = lane >> 4;
    const int r0 = (blockIdx.x * 4 + (t >> 6)) << 4;
    if (r0 >= M) return;

    f32x4 acc[NT];
#pragma unroll
    for (int nt = 0; nt < NT; ++nt) acc[nt] = (f32x4){0.f, 0.f, 0.f, 0.f};

#pragma unroll
    for (int s = 0; s < 4; ++s) {
        short8 a;
        if (FP32A) {
            const float* Af = (const float*)Av + (size_t)(r0 + dn) * 128 + s * 32 + kg * 8;
            float4 x0 = *reinterpret_cast<const float4*>(Af);
            float4 x1 = *reinterpret_cast<const float4*>(Af + 4);
            a[0] = (short)f2bf(x0.x); a[1] = (short)f2bf(x0.y);
            a[2] = (short)f2bf(x0.z); a[3] = (short)f2bf(x0.w);
            a[4] = (short)f2bf(x1.x); a[5] = (short)f2bf(x1.y);
            a[6] = (short)f2bf(x1.z); a[7] = (short)f2bf(x1.w);
        } else {
            a = *reinterpret_cast<const short8*>(
                (const u16*)Av + (size_t)(r0 + dn) * 128 + s * 32 + kg * 8);
        }
#pragma unroll
        for (int nt = 0; nt < NT; ++nt) {
            short8 b = *reinterpret_cast<const short8*>(
                &wlds[(nt * 16 + dn) * LSTR + s * 32 + kg * 8]);
            acc[nt] = __builtin_amdgcn_mfma_f32_16x16x32_bf16(b, a, acc[nt], 0, 0, 0);
        }
    }

    const int row = r0 + dn;
#pragma unroll
    for (int nt = 0; nt < NT; ++nt) {
        float v0 = acc[nt][0], v1 = acc[nt][1], v2 = acc[nt][2], v3 = acc[nt][3];
        if (RELU) {
            v0 = fmaxf(v0, 0.f); v1 = fmaxf(v1, 0.f);
            v2 = fmaxf(v2, 0.f); v3 = fmaxf(v3, 0.f);
        }
        if (OUT_BF16) {
            uint2 p; p.x = pack2bf(v0, v1); p.y = pack2bf(v2, v3);
            *reinterpret_cast<uint2*>(
                (u16*)out + (size_t)row * NC + nt * 16 + kg * 4) = p;
        } else {
            float4 p = make_float4(v0, v1, v2, v3);
            *reinterpret_cast<float4*>(
                (float*)out + (size_t)row * NC + nt * 16 + kg * 4) = p;
        }
    }
}

// ---------- Fused GEMM2+GEMM3: out = relu(Y @ W2) @ W3, no h2 round-trip ----------
__global__ __launch_bounds__(256, 3)
void gemm23_kernel(const u16* __restrict__ A, const u16* __restrict__ WT2,
                   const u16* __restrict__ WT3, float* __restrict__ out, int M) {
    constexpr int LSTR = 136;
    __shared__ u16 w2l[128 * LSTR];           // 34816 B
    __shared__ u16 h2l[4][16 * LSTR];         // 17408 B (4.3KB per wave, private)

    const int t = threadIdx.x;
    const int fr = t & 15;
#pragma unroll
    for (int n = t >> 4; n < 128; n += 16)
        *reinterpret_cast<uint4*>(&w2l[n * LSTR + fr * 8]) =
            *reinterpret_cast<const uint4*>(&WT2[(size_t)n * 128 + fr * 8]);

    const int wave = t >> 6;
    const int lane = t & 63;
    const int dn = lane & 15;
    const int kg = lane >> 4;

    short8 bw3[4][4];
#pragma unroll
    for (int nt = 0; nt < 4; ++nt)
#pragma unroll
        for (int s = 0; s < 4; ++s)
            bw3[nt][s] = *reinterpret_cast<const short8*>(
                &WT3[(size_t)(nt * 16 + dn) * 128 + s * 32 + kg * 8]);

    __syncthreads();

    const int r0 = (blockIdx.x * 4 + wave) << 4;
    if (r0 >= M) return;

    f32x4 acc2[8];
#pragma unroll
    for (int nt = 0; nt < 8; ++nt) acc2[nt] = (f32x4){0.f, 0.f, 0.f, 0.f};
#pragma unroll
    for (int s = 0; s < 4; ++s) {
        short8 a = *reinterpret_cast<const short8*>(
            &A[(size_t)(r0 + dn) * 128 + s * 32 + kg * 8]);
#pragma unroll
        for (int nt = 0; nt < 8; ++nt) {
            short8 b = *reinterpret_cast<const short8*>(
                &w2l[(nt * 16 + dn) * LSTR + s * 32 + kg * 8]);
            acc2[nt] = __builtin_amdgcn_mfma_f32_16x16x32_bf16(b, a, acc2[nt], 0, 0, 0);
        }
    }

    u16* my = h2l[wave];
#pragma unroll
    for (int nt = 0; nt < 8; ++nt) {
        float v0 = fmaxf(acc2[nt][0], 0.f), v1 = fmaxf(acc2[nt][1], 0.f);
        float v2 = fmaxf(acc2[nt][2], 0.f), v3 = fmaxf(acc2[nt][3], 0.f);
        uint2 p; p.x = pack2bf(v0, v1); p.y = pack2bf(v2, v3);
        *reinterpret_cast<uint2*>(&my[dn * LSTR + nt * 16 + kg * 4]) = p;
    }

    f32x4 acc3[4];
#pragma unroll
    for (int nt = 0; nt < 4; ++nt) acc3[nt] = (f32x4){0.f, 0.f, 0.f, 0.f};
#pragma unroll
    for (int s = 0; s < 4; ++s) {
        short8 a = *reinterpret_cast<const short8*>(
            &my[dn * LSTR + s * 32 + kg * 8]);
#pragma unroll
        for (int nt = 0; nt < 4; ++nt)
            acc3[nt] = __builtin_amdgcn_mfma_f32_16x16x32_bf16(bw3[nt][s], a, acc3[nt], 0, 0, 0);
    }

    const int row = r0 + dn;
#pragma unroll
    for (int nt = 0; nt < 4; ++nt)
        *reinterpret_cast<float4*>(out + (size_t)row * 64 + nt * 16 + kg * 4) =
            make_float4(acc3[nt][0], acc3[nt][1], acc3[nt][2], acc3[nt][3]);
}

extern "C" void kernel_launch(void* const* d_in, const int* in_sizes, int n_in,
                              void* d_out, int out_size, void* d_ws, size_t ws_size,
                              hipStream_t stream) {
    const float* x    = (const float*)d_in[0];
    const float* w1   = (const float*)d_in[1];
    const float* w2   = (const float*)d_in[2];
    const float* w3   = (const float*)d_in[3];
    const int*   erow = (const int*)d_in[4];
    const int*   ecol = (const int*)d_in[5];
    const float* eval = (const float*)d_in[6];
    float* out = (float*)d_out;

    const int N = in_sizes[0] / FDIM;
    const int E = in_sizes[4];

    char* ws = (char*)d_ws;
    int* rowptr = (int*)ws;                                  // (N+1)*4
    u16* wt1 = (u16*)(ws + (512 << 10));                     // 32KB
    u16* wt2 = wt1 + 128 * 128;                              // 32KB
    u16* wt3 = wt2 + 128 * 128;                              // 16KB
    u16* zbuf = (u16*)(ws + (1 << 20));                      // 16MB bf16 [N][128]
    u16* hbuf = (u16*)(ws + (18u << 20));                    // 16MB bf16 [N][128]

    prep_kernel<<<417, 256, 0, stream>>>(erow, rowptr, w1, wt1, w2, wt2, w3, wt3, N, E);
    // z = x @ W1 (fp32 A direct; linearity: spmm(x)@W1 == spmm(x@W1))
    gemm_kernel<8, false, true, true><<<N / 64, 256, 0, stream>>>(x, wt1, zbuf, N);
    // h1 = relu(spmm(z))
    spmm_kernel<true><<<N / 4, 256, 0, stream>>>(zbuf, rowptr, ecol, eval, hbuf, N);
    // y = spmm(h1)
    spmm_kernel<false><<<N / 4, 256, 0, stream>>>(hbuf, rowptr, ecol, eval, zbuf, N);
    // out = relu(y @ W2) @ W3
    gemm23_kernel<<<N / 64, 256, 0, stream>>>(zbuf, wt2, wt3, out, N);
}